// Round 19
// baseline (206.250 us; speedup 1.0000x reference)
//
#include <hip/hip_runtime.h>
#include <hip/hip_bf16.h>

#define MDIM 4096
#define DDIM 2048
#define HDIM 2048
#define EDIM 8
#define HD   ((size_t)HDIM * DDIM)

typedef float v4f __attribute__((ext_vector_type(4)));
typedef int   v4i __attribute__((ext_vector_type(4)));
typedef int   v8i __attribute__((ext_vector_type(8)));

// async global->LDS, 16B per lane. lds pointer must be wave-uniform
// (HW writes base + lane*16).
__device__ __forceinline__ void gl2lds16(const void* g, void* l) {
  __builtin_amdgcn_global_load_lds(
      (const __attribute__((address_space(1))) void*)g,
      (__attribute__((address_space(3))) void*)l,
      16, 0, 0);
}

// ------------- Kernel 1: fused {gating softmax + x fp8} | {w fp8} ------------
__global__ __launch_bounds__(256) void k_quant(
    const float* __restrict__ x, const float* __restrict__ gw,
    const float* __restrict__ gb, const float* __restrict__ w,
    float* __restrict__ gate, unsigned char* __restrict__ x8,
    unsigned char* __restrict__ w8)
{
  if (blockIdx.x < 1024) {
    const int wid  = threadIdx.x >> 6;
    const int lane = threadIdx.x & 63;
    const int m    = blockIdx.x * 4 + wid;

    const float4* xr = (const float4*)(x + (size_t)m * DDIM);
    unsigned int* qr = (unsigned int*)(x8 + (size_t)m * DDIM);

    float part[EDIM];
#pragma unroll
    for (int e = 0; e < EDIM; ++e) part[e] = 0.f;

#pragma unroll
    for (int it = 0; it < DDIM / 4 / 64; ++it) {   // 8 iterations
      const int idx = it * 64 + lane;
      const float4 xv = xr[idx];
      int pk = __builtin_amdgcn_cvt_pk_fp8_f32(xv.x, xv.y, 0, false);
      pk = __builtin_amdgcn_cvt_pk_fp8_f32(xv.z, xv.w, pk, true);
      qr[idx] = (unsigned int)pk;
#pragma unroll
      for (int e = 0; e < EDIM; ++e) {
        const float4 wv = ((const float4*)(gw + (size_t)e * DDIM))[idx];
        part[e] += xv.x * wv.x + xv.y * wv.y + xv.z * wv.z + xv.w * wv.w;
      }
    }
#pragma unroll
    for (int e = 0; e < EDIM; ++e) {
#pragma unroll
      for (int off = 32; off > 0; off >>= 1)
        part[e] += __shfl_xor(part[e], off);
    }
    float lg[EDIM];
    float s = 0.f;
#pragma unroll
    for (int e = 0; e < EDIM; ++e) lg[e] = part[e] + gb[e];
    float mx = lg[0];
#pragma unroll
    for (int e = 1; e < EDIM; ++e) mx = fmaxf(mx, lg[e]);
#pragma unroll
    for (int e = 0; e < EDIM; ++e) { lg[e] = expf(lg[e] - mx); s += lg[e]; }
    const float inv = 1.f / s;
    if (lane < EDIM) gate[m * EDIM + lane] = lg[lane] * inv;
  } else {
    const long long n4 = (long long)EDIM * HDIM * DDIM / 4;
    const long long stride = (long long)4096 * 256;
    for (long long i = (long long)(blockIdx.x - 1024) * 256 + threadIdx.x;
         i < n4; i += stride) {
      const float4 v = ((const float4*)w)[i];
      int pk = __builtin_amdgcn_cvt_pk_fp8_f32(v.x, v.y, 0, false);
      pk = __builtin_amdgcn_cvt_pk_fp8_f32(v.z, v.w, pk, true);
      ((unsigned int*)w8)[i] = (unsigned int)pk;
    }
  }
}

// ---------------- Kernel 2: fused grouped GEMM + gated combine ----------------
// R17 shell (133us GEMM, MfmaUtil 46%, VGPR 100, clean; diagnosed ~75-80%
// LDS-BW-bound: 128KB reads + 64KB gl2lds writes per CU-step vs 1104cy MFMA)
// + HALF-LDS/HALF-DIRECT B: fragments j=0,1 (rows wn*64+0..31) stay
// LDS-staged; j=2,3 (rows wn*64+32..63) load DIRECT global->VGPR inside
// COMP, issued FIRST so L2 latency (~200-300cy) hides under the j=0,1
// MFMAs (~400cy). The wm-paired wave reads identical B lines -> L1 hits.
// LDS traffic/CU-step: reads 128->96KB, writes 64->48KB (-25%). B-LDS
// buffers 16->8KB (block LDS 52KB). Direct-B regs are in-region transient
// (no fence crossing -- R16's trap avoided); arch ~115 < 128-cap.
// All else R17-identical: e-outer s=e*16+kt, A dbuf global_load_lds +
// both-sides XOR swizzle, C-chained acc (AGPR), gate fold at expert
// boundaries, one barrier/step, 256thr 2m x 2n (64x64/wave), tile 128x128,
// 512 blocks = 2 independent blocks/CU, setprio around MFMA.
__global__ __launch_bounds__(256, 2) void k_moe_gemm(
    const unsigned char* __restrict__ x8,   // [M, D]
    const unsigned char* __restrict__ w8,   // [E, H, D]
    const float* __restrict__ gate,         // [M, 8]
    float* __restrict__ out)                // [M, H] f32
{
  extern __shared__ unsigned char smem[];   // 2*16K A + 2*8K B + 4K G = 52K

  const int tid  = threadIdx.x;
  const int lane = tid & 63;
  const int wid  = tid >> 6;        // 0..3
  const int wm   = wid >> 1;        // 0..1  (64-row group)
  const int wn   = wid & 1;         // 0..1  (64-col group)

  // XCD chunking: 512 blocks; each XCD owns an 8x8 square of (m,h) tiles.
  const int bid   = blockIdx.x;
  const int xcd   = bid & 7;
  const int local = bid >> 3;                        // 0..63
  const int tm    = (xcd >> 1) * 8 + (local >> 3);   // 0..31
  const int tn    = (xcd & 1) * 8 + (local & 7);     // 0..15
  const int bm    = tm * 128;
  const int bn    = tn * 128;

  const int lrow = lane & 15;
  const int lk   = lane >> 4;                  // 0..3 -> 32B k-block
  const int c0   = (lk * 32) ^ ((lrow & 7) << 4);
  const int c1   = c0 ^ 16;

  // staging coords: thread covers row strow of each 32-row slab,
  // inverse-swizzled col stcol (involution within the 128B row).
  const int strow = tid >> 3;                  // 0..31
  const int stcol = ((tid & 7) * 16) ^ ((strow & 7) << 4);
  const unsigned char* asrc = x8 + (size_t)(bm + strow) * DDIM + stcol;
  const unsigned char* bsrc = w8 + (size_t)(bn + strow) * DDIM + stcol;

  // direct-B fragment base (rows wn*64 + j*16 + lrow, j = 2,3)
  const unsigned char* bptr =
      w8 + (size_t)(bn + wn * 64 + lrow) * DDIM + lk * 32;

  float* sGf = (float*)(smem + 48 * 1024);     // [8 experts][128 rows]

  // gate cache: threads 0..127 own row bm+tid for all 8 experts
  if (tid < 128) {
    const float4 g0 = *(const float4*)(gate + (size_t)(bm + tid) * EDIM);
    const float4 g1 = *(const float4*)(gate + (size_t)(bm + tid) * EDIM + 4);
    sGf[0 * 128 + tid] = g0.x; sGf[1 * 128 + tid] = g0.y;
    sGf[2 * 128 + tid] = g0.z; sGf[3 * 128 + tid] = g0.w;
    sGf[4 * 128 + tid] = g1.x; sGf[5 * 128 + tid] = g1.y;
    sGf[6 * 128 + tid] = g1.z; sGf[7 * 128 + tid] = g1.w;
  }

  v4f acc[4][4];      // per-expert partial, mfma C-chained (AGPR)
  v4f outacc[4][4];   // gated running sum (AGPR-foldable)
#pragma unroll
  for (int i = 0; i < 4; ++i)
#pragma unroll
    for (int j = 0; j < 4; ++j) {
      acc[i][j][0] = 0.f; acc[i][j][1] = 0.f;
      acc[i][j][2] = 0.f; acc[i][j][3] = 0.f;
      outacc[i][j][0] = 0.f; outacc[i][j][1] = 0.f;
      outacc[i][j][2] = 0.f; outacc[i][j][3] = 0.f;
    }

// stage step S: A k-tile (4 loads) + B lower-halves (2 loads) into buf[S&1].
// B LDS layout: [2 slabs wn][32 rows][128B]; slab w holds B rows w*64+0..31.
#define STAGE(S) do {                                                          \
    const int    kb_ = ((S) & 15) * 128;                                       \
    const size_t eo_ = (size_t)((S) >> 4) * HD;                                \
    unsigned char* la_ = smem + ((S) & 1) * 16384;                             \
    unsigned char* lb_ = smem + 32768 + ((S) & 1) * 8192;                      \
    _Pragma("unroll") for (int i = 0; i < 4; ++i)                              \
      gl2lds16(asrc + (size_t)i * (32 * DDIM) + kb_,                           \
               (void*)(la_ + i * 4096 + wid * 1024));                          \
    _Pragma("unroll") for (int i = 0; i < 2; ++i)                              \
      gl2lds16(bsrc + eo_ + (size_t)i * (64 * DDIM) + kb_,                     \
               (void*)(lb_ + i * 4096 + wid * 1024));                          \
  } while (0)

#define COMP(S) do {                                                           \
    const int e_ = (S) >> 4;                                                   \
    /* direct-global B fragments j=2,3 -- issued FIRST (latency cover) */      \
    const unsigned char* pb2_ = bptr + (size_t)e_ * HD +                       \
                                (size_t)(((S) & 15) * 128) +                   \
                                (size_t)2 * (16 * DDIM);                       \
    v8i gb2_, gb3_;                                                            \
    { union { v8i v; v4i h[2]; } u_;                                           \
      u_.h[0] = *(const v4i*)(pb2_); u_.h[1] = *(const v4i*)(pb2_ + 16);       \
      gb2_ = u_.v; }                                                           \
    { const unsigned char* pb3_ = pb2_ + (16 * DDIM);                          \
      union { v8i v; v4i h[2]; } u_;                                           \
      u_.h[0] = *(const v4i*)(pb3_); u_.h[1] = *(const v4i*)(pb3_ + 16);       \
      gb3_ = u_.v; }                                                           \
    const unsigned char* pA_ = smem + ((S) & 1) * 16384 +                      \
                               (size_t)(wm * 64 + lrow) * 128;                 \
    const unsigned char* pB_ = smem + 32768 + ((S) & 1) * 8192 +               \
                               (size_t)(wn * 4096 + lrow * 128);               \
    v8i bv_[2];                                                                \
    _Pragma("unroll") for (int j = 0; j < 2; ++j) {                            \
      union { v8i v; v4i h[2]; } u_;                                           \
      u_.h[0] = *(const v4i*)(pB_ + j * 2048 + c0);                            \
      u_.h[1] = *(const v4i*)(pB_ + j * 2048 + c1);                            \
      bv_[j] = u_.v;                                                           \
    }                                                                          \
    v8i av_[4];                                                                \
    _Pragma("unroll") for (int i = 0; i < 4; ++i) {                            \
      union { v8i v; v4i h[2]; } u_;                                           \
      u_.h[0] = *(const v4i*)(pA_ + i * 2048 + c0);                            \
      u_.h[1] = *(const v4i*)(pA_ + i * 2048 + c1);                            \
      av_[i] = u_.v;                                                           \
    }                                                                          \
    __builtin_amdgcn_s_setprio(1);                                             \
    _Pragma("unroll") for (int i = 0; i < 4; ++i)                              \
      acc[i][0] = __builtin_amdgcn_mfma_scale_f32_16x16x128_f8f6f4(            \
          av_[i], bv_[0], acc[i][0], 0, 0, 0, 127, 0, 127);                    \
    _Pragma("unroll") for (int i = 0; i < 4; ++i)                              \
      acc[i][1] = __builtin_amdgcn_mfma_scale_f32_16x16x128_f8f6f4(            \
          av_[i], bv_[1], acc[i][1], 0, 0, 0, 127, 0, 127);                    \
    _Pragma("unroll") for (int i = 0; i < 4; ++i)                              \
      acc[i][2] = __builtin_amdgcn_mfma_scale_f32_16x16x128_f8f6f4(            \
          av_[i], gb2_, acc[i][2], 0, 0, 0, 127, 0, 127);                      \
    _Pragma("unroll") for (int i = 0; i < 4; ++i)                              \
      acc[i][3] = __builtin_amdgcn_mfma_scale_f32_16x16x128_f8f6f4(            \
          av_[i], gb3_, acc[i][3], 0, 0, 0, 127, 0, 127);                      \
    __builtin_amdgcn_s_setprio(0);                                             \
    if (((S) & 15) == 15) {     /* expert boundary: fold gate, reset acc */    \
      _Pragma("unroll") for (int i = 0; i < 4; ++i) {                          \
        const v4f g4_ =                                                        \
            *(const v4f*)(sGf + e_ * 128 + wm * 64 + i * 16 + lk * 4);         \
        _Pragma("unroll") for (int j = 0; j < 4; ++j) {                        \
          outacc[i][j][0] += g4_[0] * acc[i][j][0]; acc[i][j][0] = 0.f;        \
          outacc[i][j][1] += g4_[1] * acc[i][j][1]; acc[i][j][1] = 0.f;        \
          outacc[i][j][2] += g4_[2] * acc[i][j][2]; acc[i][j][2] = 0.f;        \
          outacc[i][j][3] += g4_[3] * acc[i][j][3]; acc[i][j][3] = 0.f;        \
        }                                                                      \
      }                                                                        \
    }                                                                          \
  } while (0)

  // prologue: stage step 0; publish gate cache; drain
  STAGE(0);
  __syncthreads();

  // main loop: ONE barrier per step; stage-after-barrier (race-free)
  for (int s = 0; s < 128; ++s) {
    asm volatile("s_waitcnt vmcnt(0)" ::: "memory");
    __builtin_amdgcn_s_barrier();
    if (s < 127) STAGE(s + 1);
    COMP(s);
  }

#undef COMP
#undef STAGE

  // epilogue: direct coalesced stores (single block per output tile)
#pragma unroll
  for (int i = 0; i < 4; ++i)
#pragma unroll
    for (int q = 0; q < 4; ++q) {
      const size_t r = (size_t)(bm + wm * 64 + i * 16 + lk * 4 + q);
      float* orow = out + r * HDIM + bn + wn * 64 + lrow;
#pragma unroll
      for (int j = 0; j < 4; ++j)
        orow[j * 16] = outacc[i][j][q];
    }
}

extern "C" void kernel_launch(void* const* d_in, const int* in_sizes, int n_in,
                              void* d_out, int out_size, void* d_ws, size_t ws_size,
                              hipStream_t stream) {
  (void)in_sizes; (void)n_in; (void)out_size; (void)ws_size;
  const float* x        = (const float*)d_in[0];
  const float* gate_w   = (const float*)d_in[1];
  const float* gate_b   = (const float*)d_in[2];
  const float* expert_w = (const float*)d_in[3];
  float* out = (float*)d_out;

  char* ws = (char*)d_ws;
  float* gate       = (float*)ws;                                   // 131072 B
  unsigned char* x8 = (unsigned char*)(ws + 131072);                // 8 MiB
  unsigned char* w8 = (unsigned char*)(ws + 131072 + (size_t)MDIM * DDIM);

  hipLaunchKernelGGL(k_quant, dim3(5120), dim3(256), 0, stream,
                     x, gate_w, gate_b, expert_w, gate, x8, w8);
  hipLaunchKernelGGL(k_moe_gemm, dim3(512), dim3(256), 53248, stream,
                     x8, w8, gate, out);
}

// Round 20
// 159.494 us; speedup vs baseline: 1.2931x; 1.2931x over previous
//
#include <hip/hip_runtime.h>
#include <hip/hip_bf16.h>

#define MDIM 4096
#define DDIM 2048
#define HDIM 2048
#define EDIM 8
#define HD   ((size_t)HDIM * DDIM)

typedef float v4f __attribute__((ext_vector_type(4)));
typedef int   v4i __attribute__((ext_vector_type(4)));
typedef int   v8i __attribute__((ext_vector_type(8)));

// async global->LDS, 16B per lane. lds pointer must be wave-uniform
// (HW writes base + lane*16).
__device__ __forceinline__ void gl2lds16(const void* g, void* l) {
  __builtin_amdgcn_global_load_lds(
      (const __attribute__((address_space(1))) void*)g,
      (__attribute__((address_space(3))) void*)l,
      16, 0, 0);
}

// ------------- Kernel 1: fused {gating softmax + x fp8} | {w fp8} ------------
// blocks 0..1023: gate+xq (1 wave per row). blocks 1024..5119: w quantize.
// Both HBM-streaming and independent; combined ~160MB reads ~= 26us, at the
// stream floor.
__global__ __launch_bounds__(256) void k_quant(
    const float* __restrict__ x, const float* __restrict__ gw,
    const float* __restrict__ gb, const float* __restrict__ w,
    float* __restrict__ gate, unsigned char* __restrict__ x8,
    unsigned char* __restrict__ w8)
{
  if (blockIdx.x < 1024) {
    const int wid  = threadIdx.x >> 6;
    const int lane = threadIdx.x & 63;
    const int m    = blockIdx.x * 4 + wid;

    const float4* xr = (const float4*)(x + (size_t)m * DDIM);
    unsigned int* qr = (unsigned int*)(x8 + (size_t)m * DDIM);

    float part[EDIM];
#pragma unroll
    for (int e = 0; e < EDIM; ++e) part[e] = 0.f;

#pragma unroll
    for (int it = 0; it < DDIM / 4 / 64; ++it) {   // 8 iterations
      const int idx = it * 64 + lane;
      const float4 xv = xr[idx];
      int pk = __builtin_amdgcn_cvt_pk_fp8_f32(xv.x, xv.y, 0, false);
      pk = __builtin_amdgcn_cvt_pk_fp8_f32(xv.z, xv.w, pk, true);
      qr[idx] = (unsigned int)pk;
#pragma unroll
      for (int e = 0; e < EDIM; ++e) {
        const float4 wv = ((const float4*)(gw + (size_t)e * DDIM))[idx];
        part[e] += xv.x * wv.x + xv.y * wv.y + xv.z * wv.z + xv.w * wv.w;
      }
    }
#pragma unroll
    for (int e = 0; e < EDIM; ++e) {
#pragma unroll
      for (int off = 32; off > 0; off >>= 1)
        part[e] += __shfl_xor(part[e], off);
    }
    float lg[EDIM];
    float s = 0.f;
#pragma unroll
    for (int e = 0; e < EDIM; ++e) lg[e] = part[e] + gb[e];
    float mx = lg[0];
#pragma unroll
    for (int e = 1; e < EDIM; ++e) mx = fmaxf(mx, lg[e]);
#pragma unroll
    for (int e = 0; e < EDIM; ++e) { lg[e] = expf(lg[e] - mx); s += lg[e]; }
    const float inv = 1.f / s;
    if (lane < EDIM) gate[m * EDIM + lane] = lg[lane] * inv;
  } else {
    const long long n4 = (long long)EDIM * HDIM * DDIM / 4;
    const long long stride = (long long)4096 * 256;
    for (long long i = (long long)(blockIdx.x - 1024) * 256 + threadIdx.x;
         i < n4; i += stride) {
      const float4 v = ((const float4*)w)[i];
      int pk = __builtin_amdgcn_cvt_pk_fp8_f32(v.x, v.y, 0, false);
      pk = __builtin_amdgcn_cvt_pk_fp8_f32(v.z, v.w, pk, true);
      ((unsigned int*)w8)[i] = (unsigned int)pk;
    }
  }
}

// ---------------- Kernel 2: fused grouped GEMM + gated combine ----------------
// CONVERGED STRUCTURE (best of 20 rounds: 133us GEMM, 2067 TF = 44% of the
// 4686 TF MX-fp8 ceiling, MfmaUtil 46%, VGPR 100 arch + 128 AGPR, no spill).
// Design laws established by R5-R19 on this compiler/HW:
//  - only MFMA-C-chained (AGPR) state may be loop-carried across barriers;
//    any ds/global-produced register crossing a fence -> 128-arch-cap spill
//    (6 reproductions: R6,R7,R8,R9,R12,R13,R16).
//  - B must be LDS-prefetched: every direct-global-B variant exposes L2
//    latency in-step (R13,R15,R19) or spills when reg-prefetched (R16).
//  - step time 2494cy vs MFMA 1104cy + LDS 128KB-read/64KB-write ~1700cy:
//    LDS-port-bound; barrier-count/ordering/phase tweaks are null (R17,R18).
// Structure: e-outer linear steps s=e*16+kt; A/B double-buffered via
// global_load_lds with both-sides XOR swizzle (T2, +4.2x at R2); MX-scaled
// mfma 16x16x128 fp8 with unit e8m0 scales (2x rate, exact vs reference's
// dequantized-f32 einsum); C-chained acc -> gate folded into outacc at
// expert boundaries (bf16-round skip bounded ~2^-9|y|, absmax 0.0156);
// one barrier per step (stage-after-barrier, race-free); 256 thr, 4 waves
// 2m x 2n (64x64/wave), tile 128x128, 512 blocks = 2 independent blocks/CU
// (TLP +28% at R11); XCD-chunked block mapping (T1).
__global__ __launch_bounds__(256, 2) void k_moe_gemm(
    const unsigned char* __restrict__ x8,   // [M, D]
    const unsigned char* __restrict__ w8,   // [E, H, D]
    const float* __restrict__ gate,         // [M, 8]
    float* __restrict__ out)                // [M, H] f32
{
  extern __shared__ unsigned char smem[];   // 2*16K A + 2*16K B + 4K G = 68K

  const int tid  = threadIdx.x;
  const int lane = tid & 63;
  const int wid  = tid >> 6;        // 0..3
  const int wm   = wid >> 1;        // 0..1  (64-row group)
  const int wn   = wid & 1;         // 0..1  (64-col group)

  // XCD chunking: 512 blocks; each XCD owns an 8x8 square of (m,h) tiles.
  const int bid   = blockIdx.x;
  const int xcd   = bid & 7;
  const int local = bid >> 3;                        // 0..63
  const int tm    = (xcd >> 1) * 8 + (local >> 3);   // 0..31
  const int tn    = (xcd & 1) * 8 + (local & 7);     // 0..15
  const int bm    = tm * 128;
  const int bn    = tn * 128;

  const int lrow = lane & 15;
  const int lk   = lane >> 4;                  // 0..3 -> 32B k-block
  const int c0   = (lk * 32) ^ ((lrow & 7) << 4);
  const int c1   = c0 ^ 16;

  // staging coords: thread covers row strow of each 32-row slab,
  // inverse-swizzled col stcol (involution within the 128B row).
  const int strow = tid >> 3;                  // 0..31
  const int stcol = ((tid & 7) * 16) ^ ((strow & 7) << 4);
  const unsigned char* asrc = x8 + (size_t)(bm + strow) * DDIM + stcol;
  const unsigned char* bsrc = w8 + (size_t)(bn + strow) * DDIM + stcol;

  float* sGf = (float*)(smem + 65536);         // [8 experts][128 rows]

  // gate cache: threads 0..127 own row bm+tid for all 8 experts
  if (tid < 128) {
    const float4 g0 = *(const float4*)(gate + (size_t)(bm + tid) * EDIM);
    const float4 g1 = *(const float4*)(gate + (size_t)(bm + tid) * EDIM + 4);
    sGf[0 * 128 + tid] = g0.x; sGf[1 * 128 + tid] = g0.y;
    sGf[2 * 128 + tid] = g0.z; sGf[3 * 128 + tid] = g0.w;
    sGf[4 * 128 + tid] = g1.x; sGf[5 * 128 + tid] = g1.y;
    sGf[6 * 128 + tid] = g1.z; sGf[7 * 128 + tid] = g1.w;
  }

  v4f acc[4][4];      // per-expert partial, mfma C-chained (AGPR)
  v4f outacc[4][4];   // gated running sum (AGPR-foldable)
#pragma unroll
  for (int i = 0; i < 4; ++i)
#pragma unroll
    for (int j = 0; j < 4; ++j) {
      acc[i][j][0] = 0.f; acc[i][j][1] = 0.f;
      acc[i][j][2] = 0.f; acc[i][j][3] = 0.f;
      outacc[i][j][0] = 0.f; outacc[i][j][1] = 0.f;
      outacc[i][j][2] = 0.f; outacc[i][j][3] = 0.f;
    }

// stage step S (A k-tile + B tile) into buf[S&1]: 4 + 4 loads/thread
#define STAGE(S) do {                                                          \
    const int    kb_ = ((S) & 15) * 128;                                       \
    const size_t eo_ = (size_t)((S) >> 4) * HD;                                \
    unsigned char* la_ = smem + ((S) & 1) * 16384;                             \
    unsigned char* lb_ = smem + 32768 + ((S) & 1) * 16384;                     \
    _Pragma("unroll") for (int i = 0; i < 4; ++i)                              \
      gl2lds16(asrc + (size_t)i * (32 * DDIM) + kb_,                           \
               (void*)(la_ + i * 4096 + wid * 1024));                          \
    _Pragma("unroll") for (int i = 0; i < 4; ++i)                              \
      gl2lds16(bsrc + eo_ + (size_t)i * (32 * DDIM) + kb_,                     \
               (void*)(lb_ + i * 4096 + wid * 1024));                          \
  } while (0)

#define COMP(S) do {                                                           \
    const unsigned char* pA_ = smem + ((S) & 1) * 16384 +                      \
                               (size_t)(wm * 64 + lrow) * 128;                 \
    const unsigned char* pB_ = smem + 32768 + ((S) & 1) * 16384 +              \
                               (size_t)(wn * 64 + lrow) * 128;                 \
    v8i bv_[4];                                                                \
    _Pragma("unroll") for (int j = 0; j < 4; ++j) {                            \
      union { v8i v; v4i h[2]; } u_;                                           \
      u_.h[0] = *(const v4i*)(pB_ + j * 2048 + c0);                            \
      u_.h[1] = *(const v4i*)(pB_ + j * 2048 + c1);                            \
      bv_[j] = u_.v;                                                           \
    }                                                                          \
    __builtin_amdgcn_s_setprio(1);                                             \
    _Pragma("unroll") for (int i = 0; i < 4; ++i) {                            \
      union { v8i v; v4i h[2]; } ua_;                                          \
      ua_.h[0] = *(const v4i*)(pA_ + i * 2048 + c0);                           \
      ua_.h[1] = *(const v4i*)(pA_ + i * 2048 + c1);                           \
      const v8i av_ = ua_.v;                                                   \
      _Pragma("unroll") for (int j = 0; j < 4; ++j)                            \
        acc[i][j] = __builtin_amdgcn_mfma_scale_f32_16x16x128_f8f6f4(          \
            av_, bv_[j], acc[i][j], 0 /*fp8*/, 0 /*fp8*/,                      \
            0, 127 /*e8m0 1.0*/, 0, 127 /*e8m0 1.0*/);                         \
    }                                                                          \
    __builtin_amdgcn_s_setprio(0);                                             \
    if (((S) & 15) == 15) {     /* expert boundary: fold gate, reset acc */    \
      const int e_ = (S) >> 4;                                                 \
      _Pragma("unroll") for (int i = 0; i < 4; ++i) {                          \
        const v4f g4_ =                                                        \
            *(const v4f*)(sGf + e_ * 128 + wm * 64 + i * 16 + lk * 4);         \
        _Pragma("unroll") for (int j = 0; j < 4; ++j) {                        \
          outacc[i][j][0] += g4_[0] * acc[i][j][0]; acc[i][j][0] = 0.f;        \
          outacc[i][j][1] += g4_[1] * acc[i][j][1]; acc[i][j][1] = 0.f;        \
          outacc[i][j][2] += g4_[2] * acc[i][j][2]; acc[i][j][2] = 0.f;        \
          outacc[i][j][3] += g4_[3] * acc[i][j][3]; acc[i][j][3] = 0.f;        \
        }                                                                      \
      }                                                                        \
    }                                                                          \
  } while (0)

  // prologue: stage step 0; publish gate cache; drain
  STAGE(0);
  __syncthreads();

  // main loop: ONE barrier per step; stage-after-barrier (race-free)
  for (int s = 0; s < 128; ++s) {
    asm volatile("s_waitcnt vmcnt(0)" ::: "memory");
    __builtin_amdgcn_s_barrier();
    if (s < 127) STAGE(s + 1);
    COMP(s);
  }

#undef COMP
#undef STAGE

  // epilogue: direct coalesced stores (single block per output tile)
#pragma unroll
  for (int i = 0; i < 4; ++i)
#pragma unroll
    for (int q = 0; q < 4; ++q) {
      const size_t r = (size_t)(bm + wm * 64 + i * 16 + lk * 4 + q);
      float* orow = out + r * HDIM + bn + wn * 64 + lrow;
#pragma unroll
      for (int j = 0; j < 4; ++j)
        orow[j * 16] = outacc[i][j][q];
    }
}

extern "C" void kernel_launch(void* const* d_in, const int* in_sizes, int n_in,
                              void* d_out, int out_size, void* d_ws, size_t ws_size,
                              hipStream_t stream) {
  (void)in_sizes; (void)n_in; (void)out_size; (void)ws_size;
  const float* x        = (const float*)d_in[0];
  const float* gate_w   = (const float*)d_in[1];
  const float* gate_b   = (const float*)d_in[2];
  const float* expert_w = (const float*)d_in[3];
  float* out = (float*)d_out;

  char* ws = (char*)d_ws;
  float* gate       = (float*)ws;                                   // 131072 B
  unsigned char* x8 = (unsigned char*)(ws + 131072);                // 8 MiB
  unsigned char* w8 = (unsigned char*)(ws + 131072 + (size_t)MDIM * DDIM);

  hipLaunchKernelGGL(k_quant, dim3(5120), dim3(256), 0, stream,
                     x, gate_w, gate_b, expert_w, gate, x8, w8);
  hipLaunchKernelGGL(k_moe_gemm, dim3(512), dim3(256), 69632, stream,
                     x8, w8, gate, out);
}